// Round 6
// baseline (244.883 us; speedup 1.0000x reference)
//
#include <hip/hip_runtime.h>

#define VOL   2097152          // 128*128*128
#define TBL   4194304          // BATCH * VOL
#define D1D2  16384
#define DD2   128
#define TILE  128

typedef __bf16 bf16_t;
typedef bf16_t bf16x8 __attribute__((ext_vector_type(8)));
typedef float  floatx4 __attribute__((ext_vector_type(4)));

// ---------------- prep: table build + weight cvt ----------------
// table must be memset to -1 before this dispatch (stream-ordered).

__global__ __launch_bounds__(256) void prep_k(const float* __restrict__ w,
                                              const int* __restrict__ idx,
                                              int* __restrict__ table,
                                              bf16_t* __restrict__ wb, int n) {
    const int b = blockIdx.x;
    const int tblB = (n + 255) >> 8;
    if (b < tblB) {
        int t = b * 256 + threadIdx.x;
        if (t < n) {
            int4 c = ((const int4*)idx)[t];                 // b, i0, i1, i2
            int p = ((c.x * 128 + c.y) * 128 + c.z) * 128 + c.w;
            table[p] = t;                                   // original voxel id
        }
    } else {
        int t = (b - tblB) * 256 + threadIdx.x;
        if (t < 27 * 64 * 64) {                             // [co][27][ci] -> [k][co][ci]
            int ci = t & 63, co = (t >> 6) & 63, k = t >> 12;
            wb[t] = (bf16_t)w[(co * 27 + k) * 64 + ci];
        }
    }
}

// ---------------- deterministic sorted compaction ----------------
// 1024 ranges of 4096 slots each.

__global__ __launch_bounds__(256) void count_k(const int* __restrict__ table,
                                               int* __restrict__ rc) {
    __shared__ int s[256];
    const int t = threadIdx.x;
    const int base = blockIdx.x * 4096 + t * 16;
    int c = 0;
    #pragma unroll
    for (int i = 0; i < 4; ++i) {
        int4 v = ((const int4*)(table + base))[i];
        c += (v.x >= 0) + (v.y >= 0) + (v.z >= 0) + (v.w >= 0);
    }
    s[t] = c;
    __syncthreads();
    for (int off = 128; off; off >>= 1) {
        if (t < off) s[t] += s[t + off];
        __syncthreads();
    }
    if (t == 0) rc[blockIdx.x] = s[0];
}

__global__ __launch_bounds__(1024) void scan_k(const int* __restrict__ rc,
                                               int* __restrict__ rb) {
    __shared__ int s[1024];
    const int t = threadIdx.x;
    int v = rc[t];
    s[t] = v;
    __syncthreads();
    int x = v;                                  // inclusive
    for (int off = 1; off < 1024; off <<= 1) {
        int y = (t >= off) ? s[t - off] : 0;
        __syncthreads();
        x += y;
        s[t] = x;
        __syncthreads();
    }
    rb[t] = x - v;                              // exclusive base per range
}

// Compact active voxels in packed (spatial) order with deterministic bases.
// ord[pos]=orig id, pkd[pos]=packed coord, table[packed]=pos.
__global__ __launch_bounds__(256) void compact_k(int* __restrict__ table,
                                                 int* __restrict__ ord,
                                                 int* __restrict__ pkd,
                                                 const int* __restrict__ rb) {
    __shared__ int s_cnt[256];
    const int t = threadIdx.x;
    const int base = blockIdx.x * 4096 + t * 16;

    int v[16];
    #pragma unroll
    for (int i = 0; i < 4; ++i)
        *(int4*)&v[i * 4] = ((const int4*)(table + base))[i];
    int cnt = 0;
    #pragma unroll
    for (int i = 0; i < 16; ++i) cnt += (v[i] >= 0);

    s_cnt[t] = cnt;
    __syncthreads();
    int x = cnt;                                // inclusive scan
    for (int off = 1; off < 256; off <<= 1) {
        int y = (t >= off) ? s_cnt[t - off] : 0;
        __syncthreads();
        x += y;
        s_cnt[t] = x;
        __syncthreads();
    }

    int pos = rb[blockIdx.x] + x - cnt;         // global exclusive offset
    #pragma unroll
    for (int i = 0; i < 16; ++i) {
        if (v[i] >= 0) {
            ord[pos] = v[i];
            pkd[pos] = base + i;
            table[base + i] = pos;
            ++pos;
        }
    }
}

// features permuted into compacted (spatial) order, fp32 -> bf16
__global__ void feat_k(const float* __restrict__ f, const int* __restrict__ ord,
                       bf16_t* __restrict__ fbp, int n) {
    int t = blockIdx.x * blockDim.x + threadIdx.x;      // unit = (pos, 8-ch chunk)
    int pos = t >> 3, c = (t & 7) * 8;
    if (pos < n) {
        int orig = ord[pos];
        const float* src = f + (size_t)orig * 64 + c;
        float4 a  = *(const float4*)src;
        float4 b2 = *(const float4*)(src + 4);
        bf16x8 o = { (bf16_t)a.x,  (bf16_t)a.y,  (bf16_t)a.z,  (bf16_t)a.w,
                     (bf16_t)b2.x, (bf16_t)b2.y, (bf16_t)b2.z, (bf16_t)b2.w };
        *(bf16x8*)(fbp + (size_t)pos * 64 + c) = o;
    }
}

// ---------------- main conv kernel ----------------
// block = 256 thr (4 waves); tile = 128 voxels (compacted order) x 64 out-ch
// wave w: m = co in [w*16, w*16+16), n = 128 voxels (8 groups of 16)
// mfma_f32_16x16x32_bf16: D col=lane&15, row=quad*4+reg (m89/m91-verified)

__global__ __launch_bounds__(256) void conv_k(
        const bf16_t* __restrict__ fbp, const bf16_t* __restrict__ wb,
        const int* __restrict__ table, const int* __restrict__ pkd,
        const int* __restrict__ ord, const float* __restrict__ bias,
        float* __restrict__ out, int n)
{
    __shared__ int    s_pkd[TILE];
    __shared__ int    s_ord[TILE];
    __shared__ int    s_nbr[27 * TILE];   // compacted neighbor positions
    __shared__ bf16_t sF[TILE * 72];      // gathered features (pad 64->72)
    __shared__ bf16_t sW[64 * 72];        // W_k tile

    const int t    = threadIdx.x;
    const int tile = blockIdx.x * TILE;

    if (t < TILE) {
        int vn = tile + t;
        s_pkd[t] = (vn < n) ? pkd[vn] : (int)0xC0000000;  // sentinel: all taps miss
        s_ord[t] = (vn < n) ? ord[vn] : 0;
    }
    __syncthreads();

    // precompute all 27*TILE neighbor lookups (coalesced: s_pkd sorted)
    for (int u = t; u < 27 * TILE; u += 256) {
        int k  = u >> 7;                  // TILE == 128
        int r  = u & (TILE - 1);
        int k0 = k / 9, k1 = (k / 3) % 3, k2 = k % 3;
        int np = s_pkd[r] + (k0 - 1) * D1D2 + (k1 - 1) * DD2 + (k2 - 1);
        s_nbr[u] = (np >= 0 && np < TBL) ? table[np] : -1;
    }

    const int lane = t & 63;
    const int w    = t >> 6;              // wave 0..3
    const int l15  = lane & 15;
    const int q    = lane >> 4;

    // staging roles: features 2 thr/row x 32 ch; weights 4 thr/row x 16 ch
    const int rF = t >> 1;                // feature row 0..127
    const int hF = t & 1;                 // half-row (32 ch = 4x bf16x8)
    const int rW = t >> 2;                // weight row (co) 0..63
    const int cW = t & 3;                 // 16-ch chunk (2x bf16x8)

    floatx4 acc[8] = {};

    __syncthreads();                      // s_nbr ready

    // prefetch tap 0
    bf16x8 pf[4] = {{}, {}, {}, {}};
    bf16x8 pw0, pw1;
    {
        int nbr = s_nbr[rF];
        if (nbr >= 0) {
            const bf16x8* src = (const bf16x8*)(fbp + (size_t)nbr * 64 + hF * 32);
            pf[0] = src[0];
            pf[1] = src[1];
            pf[2] = src[2];
            pf[3] = src[3];
        }
        const bf16x8* wsrc = (const bf16x8*)(wb + rW * 64 + cW * 16);
        pw0 = wsrc[0];
        pw1 = wsrc[1];
    }

    for (int k = 0; k < 27; ++k) {
        // commit prefetched tap k to LDS (features: 32 ch, weights: 16 ch)
        *(bf16x8*)&sF[rF * 72 + hF * 32]      = pf[0];
        *(bf16x8*)&sF[rF * 72 + hF * 32 + 8]  = pf[1];
        *(bf16x8*)&sF[rF * 72 + hF * 32 + 16] = pf[2];
        *(bf16x8*)&sF[rF * 72 + hF * 32 + 24] = pf[3];
        *(bf16x8*)&sW[rW * 72 + cW * 16]      = pw0;
        *(bf16x8*)&sW[rW * 72 + cW * 16 + 8]  = pw1;

        // issue tap k+1 loads (waited on at NEXT iteration's LDS write)
        if (k + 1 < 27) {
            int nbr = s_nbr[(k + 1) * TILE + rF];
            bf16x8 n0 = {}, n1 = {}, n2 = {}, n3 = {};
            if (nbr >= 0) {
                const bf16x8* src = (const bf16x8*)(fbp + (size_t)nbr * 64 + hF * 32);
                n0 = src[0];
                n1 = src[1];
                n2 = src[2];
                n3 = src[3];
            }
            const bf16x8* wsrc = (const bf16x8*)(wb + ((k + 1) * 64 + rW) * 64 + cW * 16);
            pw0   = wsrc[0];
            pw1   = wsrc[1];
            pf[0] = n0;
            pf[1] = n1;
            pf[2] = n2;
            pf[3] = n3;
        }

        __syncthreads();                  // staging visible

        #pragma unroll
        for (int s = 0; s < 2; ++s) {
            bf16x8 a = *(const bf16x8*)&sW[(w * 16 + l15) * 72 + s * 32 + q * 8];
            #pragma unroll
            for (int g = 0; g < 8; ++g) {
                bf16x8 bfrag = *(const bf16x8*)&sF[(g * 16 + l15) * 72 + s * 32 + q * 8];
                acc[g] = __builtin_amdgcn_mfma_f32_16x16x32_bf16(a, bfrag, acc[g], 0, 0, 0);
            }
        }

        __syncthreads();                  // MFMA reads done before next write
    }

    // epilogue: lane holds co = w*16 + q*4 + {0..3}, voxel row g*16 + l15
    float4 bs = *(const float4*)&bias[w * 16 + q * 4];
    #pragma unroll
    for (int g = 0; g < 8; ++g) {
        int vn = tile + g * 16 + l15;
        if (vn < n) {
            int orig = s_ord[g * 16 + l15];
            float4 o;
            o.x = acc[g][0] + bs.x;
            o.y = acc[g][1] + bs.y;
            o.z = acc[g][2] + bs.z;
            o.w = acc[g][3] + bs.w;
            *(float4*)&out[(size_t)orig * 64 + w * 16 + q * 4] = o;
        }
    }
}

// ---------------- launch ----------------

extern "C" void kernel_launch(void* const* d_in, const int* in_sizes, int n_in,
                              void* d_out, int out_size, void* d_ws, size_t ws_size,
                              hipStream_t stream) {
    const float* feat = (const float*)d_in[0];
    const float* wgt  = (const float*)d_in[1];
    const float* bias = (const float*)d_in[2];
    const int*   idx  = (const int*)d_in[3];
    float* out = (float*)d_out;

    const int n = in_sizes[0] / 64;          // active voxels

    // ws layout: [table 16MB][wbf 256KB][fbp 33.5MB][ord 1MB][pkd 1MB][rc 4KB][rb 4KB]
    char* ws = (char*)d_ws;
    int*    table = (int*)ws;
    bf16_t* wbf   = (bf16_t*)(ws + (size_t)TBL * 4);
    bf16_t* fbp   = (bf16_t*)(ws + (size_t)TBL * 4 + 262144);
    int*    ord   = (int*)(ws + (size_t)TBL * 4 + 262144 + (size_t)n * 128);
    int*    pkd   = ord + n;
    int*    rc    = pkd + n;
    int*    rb    = rc + 1024;

    hipMemsetAsync(table, 0xFF, (size_t)TBL * 4, stream);   // all -1

    int tblB = (n + 255) >> 8;
    prep_k<<<tblB + 432, 256, 0, stream>>>(wgt, idx, table, wbf, n);
    count_k<<<1024, 256, 0, stream>>>(table, rc);
    scan_k<<<1, 1024, 0, stream>>>(rc, rb);
    compact_k<<<1024, 256, 0, stream>>>(table, ord, pkd, rb);

    int nu = n * 8;                                          // (pos, 8ch) units
    feat_k<<<(nu + 255) / 256, 256, 0, stream>>>(feat, ord, fbp, n);

    conv_k<<<(n + TILE - 1) / TILE, 256, 0, stream>>>(fbp, wbf, table, pkd, ord, bias, out, n);
}